// Round 3
// baseline (173.491 us; speedup 1.0000x reference)
//
#include <hip/hip_runtime.h>
#include <hip/hip_cooperative_groups.h>
#include <float.h>

namespace cg = cooperative_groups;

#define N_SRC 20000
#define N_TAR 20000
#define TPB 256
#define T 16                      // targets per thread (register tile)
#define TGT_PER_BLK (TPB * T)     // 4096
#define TBLK 5                    // ceil(20000 / 4096)
#define SC 102                    // source chunks
#define CHUNK 197                 // ceil(20000 / 102); 102*197 = 20094 >= 20000
#define NBLK (TBLK * SC)          // 510 blocks = 2 blocks/CU on 256 CUs

// Single cooperative kernel.
// Phase 1: per (target-block bx, source-chunk c), each thread keeps T targets
//   in registers; one broadcast ds_read_b128 per source feeds T*(3 fma + 1 min).
//   q = 0.5*||s||^2 - t.s  so that 0.5*d2 = 0.5*||t||^2 + q.
// grid.sync()
// Phase 2: combine the SC partial mins per target, add 0.5*||t||^2,
//   block-reduce, one atomicAdd per block.
// __launch_bounds__(256, 2): 2 waves/EU = 8 waves/CU = 2 blocks/CU co-resident
// (510 <= 512), VGPR cap 256 so the 64-float tile stays in VGPRs (round-2 bug:
// VGPR_Count=44 forced AGPR spill traffic, ~2.5x VALU inflation).
__global__ __launch_bounds__(TPB, 2) void nn_fused(
    const float* __restrict__ src, const float* __restrict__ tar,
    float* __restrict__ part, float* __restrict__ out)
{
    const int bx = blockIdx.x % TBLK;
    const int c  = blockIdx.x / TBLK;

    __shared__ float4 sh[CHUNK];
    const int base = c * CHUNK;
    for (int i = threadIdx.x; i < CHUNK; i += TPB) {
        const int s = base + i;
        float x = 0.f, y = 0.f, z = 0.f, w = 3e38f;   // pad: never the min
        if (s < N_SRC) {
            x = src[s * 3 + 0];
            y = src[s * 3 + 1];
            z = src[s * 3 + 2];
            w = 0.5f * (x * x + y * y + z * z);
        }
        sh[i] = make_float4(x, y, z, w);
    }
    __syncthreads();

    const int t0 = bx * TGT_PER_BLK + threadIdx.x;
    float ntx[T], nty[T], ntz[T], m[T];
#pragma unroll
    for (int j = 0; j < T; ++j) {
        const int t = t0 + j * TPB;
        const bool v = t < N_TAR;
        const int ti = v ? t : 0;
        ntx[j] = v ? -tar[ti * 3 + 0] : 0.f;
        nty[j] = v ? -tar[ti * 3 + 1] : 0.f;
        ntz[j] = v ? -tar[ti * 3 + 2] : 0.f;
        m[j] = FLT_MAX;
    }

    for (int i = 0; i < CHUNK; ++i) {
        const float4 p = sh[i];
#pragma unroll
        for (int j = 0; j < T; ++j) {
            const float q = fmaf(ntx[j], p.x,
                            fmaf(nty[j], p.y,
                            fmaf(ntz[j], p.z, p.w)));
            m[j] = fminf(m[j], q);
        }
    }

#pragma unroll
    for (int j = 0; j < T; ++j) {
        const int t = t0 + j * TPB;
        if (t < N_TAR) part[c * N_TAR + t] = m[j];
    }

    if (blockIdx.x == 0 && threadIdx.x == 0) out[0] = 0.f;

    cg::this_grid().sync();

    // ---- Phase 2 ----
    const int gt = blockIdx.x * TPB + threadIdx.x;
    float contrib = 0.f;
    if (gt < N_TAR) {
        float mm = FLT_MAX;
        for (int cc = 0; cc < SC; ++cc)
            mm = fminf(mm, part[cc * N_TAR + gt]);   // coalesced per cc
        const float tx = tar[gt * 3 + 0];
        const float ty = tar[gt * 3 + 1];
        const float tz = tar[gt * 3 + 2];
        contrib = 0.5f * (tx * tx + ty * ty + tz * tz) + mm;
    }
    for (int off = 32; off > 0; off >>= 1)
        contrib += __shfl_down(contrib, off);
    __shared__ float red[TPB / 64];
    if ((threadIdx.x & 63) == 0) red[threadIdx.x >> 6] = contrib;
    __syncthreads();
    if (threadIdx.x == 0) {
        float s = 0.f;
#pragma unroll
        for (int w = 0; w < TPB / 64; ++w) s += red[w];
        atomicAdd(out, s);
    }
}

extern "C" void kernel_launch(void* const* d_in, const int* in_sizes, int n_in,
                              void* d_out, int out_size, void* d_ws, size_t ws_size,
                              hipStream_t stream) {
    const float* src = (const float*)d_in[0];  // [20000,3] fp32
    const float* tar = (const float*)d_in[1];  // [20000,3] fp32
    float* out = (float*)d_out;                // scalar fp32
    float* part = (float*)d_ws;                // SC * N_TAR floats ~ 8.2 MB

    void* args[] = { (void*)&src, (void*)&tar, (void*)&part, (void*)&out };
    hipLaunchCooperativeKernel((void*)nn_fused, dim3(NBLK), dim3(TPB),
                               args, 0, stream);
}

// Round 4
// 125.703 us; speedup vs baseline: 1.3802x; 1.3802x over previous
//
#include <hip/hip_runtime.h>
#include <float.h>

#define N_SRC 20000
#define N_TAR 20000
#define TPB 256
#define T 8                       // targets per thread: 32 live accum floats,
                                  // sized to fit the allocator's ~48-VGPR
                                  // preference (T=16 spilled at VGPR_Count=44,
                                  // 2.5x VALU inflation in rounds 2-3)
#define TGT_PER_BLK (TPB * T)     // 2048
#define TBLK 10                   // ceil(20000 / 2048)
#define SC 52                     // source chunks; TBLK*SC = 520 blocks ~ 2/CU
#define CHUNK 385                 // 52*385 = 20020 >= 20000
#define FBLOCKS ((N_TAR + TPB - 1) / TPB)   // 79

// Kernel 1: per (target-block bx, source-chunk c) partial min over the chunk.
// q = 0.5*||s||^2 - t.s  so that 0.5*d2 = 0.5*||t||^2 + q.
// Inner loop per source: 1 broadcast ds_read_b128 + T*(3 v_fma + 1 v_min).
// Also zeroes out[0] (finalize only touches it after this kernel retires).
__global__ __launch_bounds__(TPB, 4) void nn_partial_min(
    const float* __restrict__ src, const float* __restrict__ tar,
    float* __restrict__ part, float* __restrict__ out)
{
    if (blockIdx.x == 0 && blockIdx.y == 0 && threadIdx.x == 0) out[0] = 0.f;

    __shared__ float4 sh[CHUNK];
    const int c = blockIdx.y;
    const int base = c * CHUNK;
    for (int i = threadIdx.x; i < CHUNK; i += TPB) {
        const int s = base + i;
        float x = 0.f, y = 0.f, z = 0.f, w = 3e38f;   // pad: never the min
        if (s < N_SRC) {
            x = src[s * 3 + 0];
            y = src[s * 3 + 1];
            z = src[s * 3 + 2];
            w = 0.5f * (x * x + y * y + z * z);
        }
        sh[i] = make_float4(x, y, z, w);
    }
    __syncthreads();

    const int t0 = blockIdx.x * TGT_PER_BLK + threadIdx.x;
    float ntx[T], nty[T], ntz[T], m[T];
#pragma unroll
    for (int j = 0; j < T; ++j) {
        const int t = t0 + j * TPB;
        const bool v = t < N_TAR;
        const int ti = v ? t : 0;
        ntx[j] = v ? -tar[ti * 3 + 0] : 0.f;
        nty[j] = v ? -tar[ti * 3 + 1] : 0.f;
        ntz[j] = v ? -tar[ti * 3 + 2] : 0.f;
        m[j] = FLT_MAX;
    }

#pragma unroll 2
    for (int i = 0; i < CHUNK; ++i) {
        const float4 p = sh[i];
#pragma unroll
        for (int j = 0; j < T; ++j) {
            const float q = fmaf(ntx[j], p.x,
                            fmaf(nty[j], p.y,
                            fmaf(ntz[j], p.z, p.w)));
            m[j] = fminf(m[j], q);
        }
    }

#pragma unroll
    for (int j = 0; j < T; ++j) {
        const int t = t0 + j * TPB;
        if (t < N_TAR) part[c * N_TAR + t] = m[j];   // coalesced
    }
}

// Kernel 2: combine the SC chunk-mins per target, add 0.5*||t||^2,
// block-reduce, one atomicAdd per block into out[0] (zeroed by kernel 1).
__global__ __launch_bounds__(TPB) void nn_finalize(
    const float* __restrict__ tar, const float* __restrict__ part,
    float* __restrict__ out)
{
    const int t = blockIdx.x * TPB + threadIdx.x;
    float contrib = 0.f;
    if (t < N_TAR) {
        float m = FLT_MAX;
#pragma unroll
        for (int c = 0; c < SC; ++c) m = fminf(m, part[c * N_TAR + t]);
        const float tx = tar[t * 3 + 0];
        const float ty = tar[t * 3 + 1];
        const float tz = tar[t * 3 + 2];
        contrib = 0.5f * (tx * tx + ty * ty + tz * tz) + m;
    }
    for (int off = 32; off > 0; off >>= 1)
        contrib += __shfl_down(contrib, off);
    __shared__ float red[TPB / 64];
    if ((threadIdx.x & 63) == 0) red[threadIdx.x >> 6] = contrib;
    __syncthreads();
    if (threadIdx.x == 0) {
        float s = 0.f;
#pragma unroll
        for (int w = 0; w < TPB / 64; ++w) s += red[w];
        atomicAdd(out, s);
    }
}

extern "C" void kernel_launch(void* const* d_in, const int* in_sizes, int n_in,
                              void* d_out, int out_size, void* d_ws, size_t ws_size,
                              hipStream_t stream) {
    const float* src = (const float*)d_in[0];  // [20000,3] fp32
    const float* tar = (const float*)d_in[1];  // [20000,3] fp32
    float* out = (float*)d_out;                // scalar fp32
    float* part = (float*)d_ws;                // SC * N_TAR floats ~ 4.16 MB

    dim3 grid1(TBLK, SC);
    nn_partial_min<<<grid1, TPB, 0, stream>>>(src, tar, part, out);
    nn_finalize<<<FBLOCKS, TPB, 0, stream>>>(tar, part, out);
}